// Round 12
// baseline (839.486 us; speedup 1.0000x reference)
//
#include <hip/hip_runtime.h>
#include <hip/hip_bf16.h>
#include <hip/hip_cooperative_groups.h>

namespace cg = cooperative_groups;

using u16 = unsigned short;
using short8 = __attribute__((ext_vector_type(8))) short;
using f32x4  = __attribute__((ext_vector_type(4))) float;

constexpr int DI_ = 384;

// ---- workspace layout ----
constexpr size_t O_XZ   = 0;                         // xz bf16 (8192*384 u16); later dtt f32
constexpr size_t O_XCT  = O_XZ  + (size_t)8192*384;  // xct bf16 [384][8192] u16
constexpr size_t O_ZST  = O_XCT + (size_t)384*8192;  // zst bf16 [384][8192] u16
constexpr size_t O_DBLT = O_ZST + (size_t)384*8192;  // 32*8192  Bs/Cs transposed f32
constexpr size_t O_YFT  = O_DBLT+ (size_t)32*8192;   // yf bf16 [384][8192] u16
constexpr size_t O_B16  = O_YFT + (size_t)384*8192;  // bf16 arena start
constexpr size_t O_DTT  = O_XZ;                      // overlays dead xz (f32)
// bf16 arena offsets (u16)
constexpr size_t B_T1  = 0;
constexpr size_t B_T2  = B_T1  + (size_t)8192*96;
constexpr size_t B_XC  = B_T2  + (size_t)8192*192;
constexpr size_t B_XB1 = B_XC  + (size_t)8192*384;
constexpr size_t B_XB4 = B_XB1 + (size_t)8192*96;
constexpr size_t B_WT1 = B_XB4 + (size_t)8192*192;
constexpr size_t B_WT4 = B_WT1 + (size_t)9*96*96;
constexpr size_t B_INW = B_WT4 + (size_t)9*192*192;
constexpr size_t B_W2  = B_INW + (size_t)768*192;
constexpr size_t B_XP  = B_W2  + (size_t)192*96;
constexpr size_t B_WDT = B_XP  + (size_t)32*384;
constexpr size_t B_WOW = B_WDT + (size_t)384*384;

constexpr int SMEM_BYTES = 34560;   // conv phase: As 11520 + Bs 23040

__device__ __forceinline__ u16 f2b(float f) {
    __hip_bfloat16 h = __float2bfloat16(f);
    return *reinterpret_cast<u16*>(&h);
}
__device__ __forceinline__ float b2f(u16 u) {
    return __uint_as_float(((unsigned)u) << 16);
}
__device__ __forceinline__ float b2f_lo(unsigned u) { return __uint_as_float(u << 16); }
__device__ __forceinline__ float b2f_hi(unsigned u) { return __uint_as_float(u & 0xffff0000u); }

struct MegaArgs {
    const float *w1, *w4, *in_w, *w2, *xp_w, *dt_w, *w3, *out_w, *x;
    const float *g1,*b1,*m1,*v1, *g2,*b2,*m2,*v2, *g3,*b3,*m3,*v3, *g4,*b4,*m4,*v4;
    const float *cw, *cb, *dt_b, *A_log, *Dp;
    u16 *wt1, *wt4, *inwb, *w2b, *xpb, *Wdt, *Wow, *Xb1;
    u16 *t1b, *t2b, *xcb, *Xb4;
    u16 *xzb16, *xct16, *zst16, *yft16;
    float *dblt, *dtt;
    float *outp;
};

// ---------------- prep jobs ----------------
__device__ void prep_job(const MegaArgs& a, int job, int i0, int stride) {
    switch (job) {
    case 0:
        for (int i = i0; i < 9*96*96; i += stride) {
            int ci = i % 96, co = (i / 96) % 96, t = i / (96*96);
            a.wt1[i] = f2b(a.w1[((size_t)co*96 + ci)*9 + t]);
        } break;
    case 1:
        for (int i = i0; i < 9*192*192; i += stride) {
            int ci = i % 192, co = (i / 192) % 192, t = i / (192*192);
            a.wt4[i] = f2b(a.w4[((size_t)co*192 + ci)*9 + t]);
        } break;
    case 2:
        for (int i = i0; i < 768*192; i += stride) a.inwb[i] = f2b(a.in_w[i]);
        break;
    case 3:
        for (int i = i0; i < 192*96; i += stride) a.w2b[i] = f2b(a.w2[i]);
        break;
    case 4:
        for (int i = i0; i < 32*384; i += stride) {
            int r = i / 384, c = i % 384;
            a.xpb[i] = f2b(a.xp_w[(size_t)(12 + r)*384 + c]);
        } break;
    case 5:
        for (int i = i0; i < 384*384; i += stride) {
            int r = i / 384, c = i % 384;
            float s = 0.f;
            #pragma unroll
            for (int k = 0; k < 12; ++k) s += a.dt_w[r*12 + k] * a.xp_w[(size_t)k*384 + c];
            a.Wdt[i] = f2b(s);
        } break;
    case 6:
        for (int i = i0; i < 192*384; i += stride) {
            int o = i / 384, d = i % 384;
            float s = 0.f;
            for (int j = 0; j < 192; ++j) s += a.w3[(size_t)o*192 + j] * a.out_w[(size_t)j*384 + d];
            a.Wow[i] = f2b(s);
        } break;
    case 7:
        for (int i = i0; i < 8192*96; i += stride) {
            int ci = i % 96, px = i / 96;
            a.Xb1[i] = f2b(a.x[(((size_t)(px >> 10) * 96 + ci) << 10) | (size_t)(px & 1023)]);
        } break;
    }
}

// ---------------- 3x3 conv body (halo-staged MFMA + BN + GELU) ----------------
// OUTM 1: f32 NCHW (LDS-transposed coalesced); 2: bf16 NHWC.
template<int CIN, int COUT, int NTILE, int OUTM>
__device__ void conv_body(
    const u16* __restrict__ Xb, const u16* __restrict__ Wt,
    const float* __restrict__ g, const float* __restrict__ b,
    const float* __restrict__ m, const float* __restrict__ v,
    void* __restrict__ out, int vbx, int vby, char* smem)
{
    constexpr int LD = 40;
    constexpr int NT = NTILE / 16;
    u16* As = (u16*)smem;                     // 4*36*40 u16 = 11520 B
    u16* Bs = (u16*)(smem + 4*36*LD*2);       // 9*NTILE*40 u16
    const int tid = threadIdx.x;
    const int wave = tid >> 6, lane = tid & 63;
    const int quad = lane >> 4, l16 = lane & 15;
    const int rowBase = vbx * 64;
    const int colBase = vby * NTILE;
    const int img = rowBase >> 10;
    const int imgRow0 = (rowBase & 1023) >> 5;

    __syncthreads();   // LDS reuse guard (prior phase / prior virtual block)
    if (tid < 160) {
        int slot8 = tid / 20;
        int off = tid % 20;
        int hrow = slot8 >> 1;
        int hcol = (slot8 & 1) ? 33 : 0;
        ((unsigned*)As)[((hrow * 36 + hcol) * LD) / 2 + off] = 0u;
    }

    f32x4 acc[NT];
    #pragma unroll
    for (int nt = 0; nt < NT; ++nt)
        #pragma unroll
        for (int i = 0; i < 4; ++i) acc[nt][i] = 0.f;

    const int pxl = wave * 16 + l16;
    const int prow = pxl >> 5, pcol = pxl & 31;

    for (int ci0 = 0; ci0 < CIN; ci0 += 32) {
        __syncthreads();
        #pragma unroll
        for (int it = 0; it < 2; ++it) {
            int id = tid + it * 256;
            int pix = id >> 2, seg = id & 3;
            int hrow = pix >> 5, hcol = pix & 31;
            int grow = imgRow0 - 1 + hrow;
            uint4 va = make_uint4(0u, 0u, 0u, 0u);
            if ((unsigned)grow < 32u)
                va = *(const uint4*)(Xb +
                    (size_t)((img << 10) + (grow << 5) + hcol) * CIN + ci0 + seg * 8);
            *(uint4*)(As + (hrow * 36 + hcol + 1) * LD + seg * 8) = va;
        }
        constexpr int BT = 9 * NTILE * 4;
        for (int id = tid; id < BT; id += 256) {
            int t = id / (NTILE * 4);
            int r = (id >> 2) & (NTILE - 1);
            int seg = id & 3;
            uint4 vb = *(const uint4*)(Wt +
                ((size_t)t * COUT + colBase + r) * CIN + ci0 + seg * 8);
            *(uint4*)(Bs + (t * NTILE + r) * LD + seg * 8) = vb;
        }
        __syncthreads();
        #pragma unroll
        for (int t = 0; t < 9; ++t) {
            const int dr = t / 3 - 1, dc = t % 3 - 1;
            short8 a = *(const short8*)(As +
                ((prow + 1 + dr) * 36 + (pcol + 1 + dc)) * LD + quad * 8);
            #pragma unroll
            for (int nt = 0; nt < NT; ++nt) {
                short8 bf = *(const short8*)(Bs + (t * NTILE + nt * 16 + l16) * LD + quad * 8);
                acc[nt] = __builtin_amdgcn_mfma_f32_16x16x32_bf16(a, bf, acc[nt], 0, 0, 0);
            }
        }
    }

    const int px0 = rowBase + wave * 16 + quad * 4;
    if (OUTM == 2) {
        #pragma unroll
        for (int nt = 0; nt < NT; ++nt) {
            const int co = colBase + nt * 16 + l16;
            const float sc = g[co] * rsqrtf(v[co] + 1e-5f);
            const float bb = b[co] - m[co] * sc;
            #pragma unroll
            for (int r = 0; r < 4; ++r) {
                float xv = acc[nt][r] * sc + bb;
                float gel = 0.5f * xv * (1.f + erff(xv * 0.70710678f));
                ((u16*)out)[(size_t)(px0 + r) * COUT + co] = f2b(gel);
            }
        }
    } else {
        float* Tout = (float*)As;   // NTILE*68*4 <= 11520 B for NTILE=32
        const int pxl0 = wave * 16 + quad * 4;
        __syncthreads();
        #pragma unroll
        for (int nt = 0; nt < NT; ++nt) {
            const int co = colBase + nt * 16 + l16;
            const float sc = g[co] * rsqrtf(v[co] + 1e-5f);
            const float bb = b[co] - m[co] * sc;
            #pragma unroll
            for (int r = 0; r < 4; ++r) {
                float xv = acc[nt][r] * sc + bb;
                Tout[(nt * 16 + l16) * 68 + pxl0 + r] =
                    0.5f * xv * (1.f + erff(xv * 0.70710678f));
            }
        }
        __syncthreads();
        const int off0 = rowBase & 1023;
        for (int s = tid; s < NTILE * 16; s += 256) {
            int co = s >> 4, p4 = s & 15;
            float4 vv = *(const float4*)(Tout + co * 68 + p4 * 4);
            *(float4*)((float*)out + (((size_t)img * COUT + colBase + co) << 10)
                       + off0 + p4 * 4) = vv;
        }
    }
}

// ---------------- shared MFMA GEMM body ----------------
// EPI: 0 none, 1 BN+SiLU, 2 softplus+bias, 3 SiLU.
// OUTM: 0 f32 row-major, 2 bf16 row-major, 3 f32 transposed, 4 bf16 transposed.
template<int NTILE, int EPI, int OUTM>
__device__ void gemm_body(
    int M, int N, int K,
    const u16* __restrict__ Ab, const u16* __restrict__ Bb, void* __restrict__ C,
    const float* __restrict__ p0, const float* __restrict__ p1,
    const float* __restrict__ p2, const float* __restrict__ p3,
    int rowBase, int colBase, u16* As, u16* Bs)
{
    constexpr int LDA = 40;
    constexpr int NT = NTILE / 16;
    const int tid = threadIdx.x;
    const int wave = tid >> 6, lane = tid & 63;
    const int quad = lane >> 4, l16 = lane & 15;

    f32x4 acc[NT];
    #pragma unroll
    for (int nt = 0; nt < NT; ++nt)
        #pragma unroll
        for (int i = 0; i < 4; ++i) acc[nt][i] = 0.f;

    const int ar = tid >> 2, aseg = tid & 3;

    for (int k0 = 0; k0 < K; k0 += 32) {
        __syncthreads();
        uint4 va = *(const uint4*)(Ab + (size_t)(rowBase + ar) * K + k0 + aseg * 8);
        *(uint4*)(As + ar * LDA + aseg * 8) = va;
        if (tid < NTILE * 4) {
            int r = tid >> 2, seg = tid & 3;
            uint4 vb = *(const uint4*)(Bb + (size_t)(colBase + r) * K + k0 + seg * 8);
            *(uint4*)(Bs + r * LDA + seg * 8) = vb;
        }
        __syncthreads();
        short8 a = *(const short8*)(As + (wave * 16 + l16) * LDA + quad * 8);
        #pragma unroll
        for (int nt = 0; nt < NT; ++nt) {
            short8 bf = *(const short8*)(Bs + (nt * 16 + l16) * LDA + quad * 8);
            acc[nt] = __builtin_amdgcn_mfma_f32_16x16x32_bf16(a, bf, acc[nt], 0, 0, 0);
        }
    }

    const int px0 = rowBase + wave * 16 + quad * 4;
    #pragma unroll
    for (int nt = 0; nt < NT; ++nt) {
        const int co = colBase + nt * 16 + l16;
        float sc = 0.f, bb = 0.f;
        if (EPI == 1) {
            sc = p0[co] * rsqrtf(p3[co] + 1e-5f);
            bb = p1[co] - p2[co] * sc;
        } else if (EPI == 2) {
            bb = p0[co];
        }
        float o[4];
        #pragma unroll
        for (int r = 0; r < 4; ++r) {
            float xv = acc[nt][r];
            if (EPI == 1) {
                xv = xv * sc + bb;
                xv = xv / (1.f + __expf(-xv));
            } else if (EPI == 2) {
                xv += bb;
                xv = (xv > 20.f) ? xv : log1pf(__expf(xv));
            } else if (EPI == 3) {
                xv = xv / (1.f + __expf(-xv));
            }
            o[r] = xv;
        }
        if (OUTM == 3) {
            *(float4*)((float*)C + (size_t)co * M + px0) =
                make_float4(o[0], o[1], o[2], o[3]);
        } else if (OUTM == 4) {
            uint2 pk;
            pk.x = (unsigned)f2b(o[0]) | ((unsigned)f2b(o[1]) << 16);
            pk.y = (unsigned)f2b(o[2]) | ((unsigned)f2b(o[3]) << 16);
            *(uint2*)((u16*)C + (size_t)co * M + px0) = pk;
        } else if (OUTM == 2) {
            #pragma unroll
            for (int r = 0; r < 4; ++r)
                ((u16*)C)[(size_t)(px0 + r) * N + co] = f2b(o[r]);
        } else {
            #pragma unroll
            for (int r = 0; r < 4; ++r)
                ((float*)C)[(size_t)(px0 + r) * N + co] = o[r];
        }
    }
}

// ---------------- out-proj body: bf16 transposed-A staging ----------------
__device__ void gemm_at_body(
    const u16* __restrict__ At, const u16* __restrict__ Bb, u16* __restrict__ C,
    const float* __restrict__ p0, const float* __restrict__ p1,
    const float* __restrict__ p2, const float* __restrict__ p3,
    int vbx, int vby, char* smem)
{
    constexpr int LDA = 40;
    constexpr int NTILE = 64, NT = 4;
    constexpr int M = 8192, N = 192, K = 384;
    u16* As = (u16*)smem;
    u16* Bs = As + 64 * LDA;
    const int tid = threadIdx.x;
    const int wave = tid >> 6, lane = tid & 63;
    const int quad = lane >> 4, l16 = lane & 15;
    const int rowBase = vbx * 64;
    const int colBase = vby * NTILE;

    f32x4 acc[NT];
    #pragma unroll
    for (int nt = 0; nt < NT; ++nt)
        #pragma unroll
        for (int i = 0; i < 4; ++i) acc[nt][i] = 0.f;

    const int krow = tid >> 3, mseg = tid & 7;

    for (int k0 = 0; k0 < K; k0 += 32) {
        __syncthreads();
        uint4 va = *(const uint4*)(At + (size_t)(k0 + krow) * M + rowBase + mseg * 8);
        const u16* pv = (const u16*)&va;
        #pragma unroll
        for (int j = 0; j < 8; ++j)
            As[(mseg * 8 + j) * LDA + krow] = pv[j];
        if (tid < NTILE * 4) {
            int r = tid >> 2, seg = tid & 3;
            uint4 vb = *(const uint4*)(Bb + (size_t)(colBase + r) * K + k0 + seg * 8);
            *(uint4*)(Bs + r * LDA + seg * 8) = vb;
        }
        __syncthreads();
        short8 a = *(const short8*)(As + (wave * 16 + l16) * LDA + quad * 8);
        #pragma unroll
        for (int nt = 0; nt < NT; ++nt) {
            short8 bf = *(const short8*)(Bs + (nt * 16 + l16) * LDA + quad * 8);
            acc[nt] = __builtin_amdgcn_mfma_f32_16x16x32_bf16(a, bf, acc[nt], 0, 0, 0);
        }
    }

    const int px0 = rowBase + wave * 16 + quad * 4;
    #pragma unroll
    for (int nt = 0; nt < NT; ++nt) {
        const int co = colBase + nt * 16 + l16;
        const float sc = p0[co] * rsqrtf(p3[co] + 1e-5f);
        const float bb = p1[co] - p2[co] * sc;
        #pragma unroll
        for (int r = 0; r < 4; ++r) {
            float xv = acc[nt][r] * sc + bb;
            xv = xv / (1.f + __expf(-xv));
            C[(size_t)(px0 + r) * N + co] = f2b(xv);
        }
    }
}

// ---------------- depthwise causal conv body ----------------
__device__ void dwconv_body(
    const u16* __restrict__ xz16, const float* __restrict__ cw, const float* __restrict__ cb,
    u16* __restrict__ xcb, u16* __restrict__ xct16, int vbx, int vby, char* smem)
{
    float* T = (float*)smem;    // [64][65] = 16640 B
    const int tid = threadIdx.x;
    const int cl = tid & 63, rq = tid >> 6;
    const int mBase = vbx * 64, cBase = vby * 64;
    const int c = cBase + cl;
    const float w0 = cw[c*4+0], w1 = cw[c*4+1], w2 = cw[c*4+2], w3 = cw[c*4+3];
    const float bias = cb[c];
    __syncthreads();
    #pragma unroll
    for (int rr = 0; rr < 16; ++rr) {
        int ml = rr * 4 + rq;
        int bl = mBase + ml;
        int l = bl & 1023;
        float acc = bias + b2f(xz16[(size_t)bl * 384 + c]) * w3;
        if (l >= 1) acc += b2f(xz16[(size_t)(bl-1) * 384 + c]) * w2;
        if (l >= 2) acc += b2f(xz16[(size_t)(bl-2) * 384 + c]) * w1;
        if (l >= 3) acc += b2f(xz16[(size_t)(bl-3) * 384 + c]) * w0;
        float s = acc / (1.f + __expf(-acc));
        xcb[(size_t)bl * DI_ + c] = f2b(s);
        T[ml * 65 + cl] = s;
    }
    __syncthreads();
    #pragma unroll
    for (int rr = 0; rr < 16; ++rr) {
        int dl = rr * 4 + rq;
        xct16[(size_t)(cBase + dl) * 8192 + mBase + cl] = f2b(T[cl * 65 + dl]);
    }
}

// ---------------- selective scan body (LDS combine, exp-of-sum) ----------------
__device__ void scan_body(
    const float* __restrict__ dtt, const float* __restrict__ dblt,
    const u16* __restrict__ xct16, const u16* __restrict__ zst16,
    const float* __restrict__ A_log, const float* __restrict__ Dp,
    u16* __restrict__ yft16, int bd, char* smem)
{
    // smem layout (floats): LH[16*257] | SD[257] | SH[16*17] | SP[16*17] | SSD[17] | AndS[16]
    float* LH  = (float*)smem;
    float* SD  = LH + 16*257;
    float* SH  = SD + 257;
    float* SP  = SH + 16*17;
    float* SSD = SP + 16*17;
    float* AndS= SSD + 17;

    const int b = bd / DI_, d = bd % DI_;
    const int tid = threadIdx.x;
    const size_t tb = (size_t)d * 8192 + (size_t)b * 1024;
    const size_t nb = (size_t)b * 1024;
    const int t4 = tid * 4;

    const float4 dt4 = *(const float4*)(dtt + tb + t4);
    const uint2 xcu = *(const uint2*)(xct16 + tb + t4);
    const float xc0 = b2f_lo(xcu.x), xc1 = b2f_hi(xcu.x);
    const float xc2 = b2f_lo(xcu.y), xc3 = b2f_hi(xcu.y);
    const float dtxc[4] = {dt4.x*xc0, dt4.y*xc1, dt4.z*xc2, dt4.w*xc3};

    float And[16];
    #pragma unroll
    for (int n = 0; n < 16; ++n) And[n] = -__expf(A_log[d*16 + n]);

    __syncthreads();
    if (tid < 16) AndS[tid] = -__expf(A_log[d*16 + tid]);
    SD[tid] = dt4.x + dt4.y + dt4.z + dt4.w;

    #pragma unroll
    for (int n = 0; n < 16; ++n) {
        const float4 bs4 = *(const float4*)(dblt + (size_t)n * 8192 + nb + t4);
        float h = dtxc[0] * bs4.x;
        h = __expf(dt4.y * And[n]) * h + dtxc[1] * bs4.y;
        h = __expf(dt4.z * And[n]) * h + dtxc[2] * bs4.z;
        h = __expf(dt4.w * And[n]) * h + dtxc[3] * bs4.w;
        LH[n * 257 + tid] = h;
    }
    __syncthreads();

    {
        const int n = tid & 15, s = tid >> 4;
        const float An = AndS[n];
        float H = 0.f, ssd = 0.f;
        #pragma unroll
        for (int k = 0; k < 16; ++k) {
            const int c = s * 16 + k;
            float sd = SD[c];
            H = __expf(An * sd) * H + LH[n * 257 + c];
            ssd += sd;
        }
        SH[n * 17 + s] = H;
        if (n == 0) SSD[s] = ssd;
    }
    __syncthreads();

    if (tid < 16) {
        const float An = AndS[tid];
        float Hp = 0.f;
        #pragma unroll
        for (int s = 0; s < 16; ++s) {
            SP[tid * 17 + s] = Hp;
            Hp = __expf(An * SSD[s]) * Hp + SH[tid * 17 + s];
        }
    }
    __syncthreads();

    {
        const int n = tid & 15, s = tid >> 4;
        const float An = AndS[n];
        float st = SP[n * 17 + s];
        #pragma unroll
        for (int k = 0; k < 16; ++k) {
            const int c = s * 16 + k;
            float a = __expf(An * SD[c]);
            float h = LH[n * 257 + c];
            LH[n * 257 + c] = st;
            st = a * st + h;
        }
    }
    __syncthreads();

    float y0 = 0.f, y1 = 0.f, y2 = 0.f, y3 = 0.f;
    #pragma unroll
    for (int n = 0; n < 16; ++n) {
        float h = LH[n * 257 + tid];
        const float4 bs4 = *(const float4*)(dblt + (size_t)n * 8192 + nb + t4);
        const float4 cs4 = *(const float4*)(dblt + (size_t)(16 + n) * 8192 + nb + t4);
        h = __expf(dt4.x * And[n]) * h + dtxc[0]*bs4.x; y0 += h * cs4.x;
        h = __expf(dt4.y * And[n]) * h + dtxc[1]*bs4.y; y1 += h * cs4.y;
        h = __expf(dt4.z * And[n]) * h + dtxc[2]*bs4.z; y2 += h * cs4.z;
        h = __expf(dt4.w * And[n]) * h + dtxc[3]*bs4.w; y3 += h * cs4.w;
    }
    const float dp = Dp[d];
    const uint2 zsu = *(const uint2*)(zst16 + tb + t4);
    float o0 = (y0 + xc0 * dp) * b2f_lo(zsu.x);
    float o1 = (y1 + xc1 * dp) * b2f_hi(zsu.x);
    float o2 = (y2 + xc2 * dp) * b2f_lo(zsu.y);
    float o3 = (y3 + xc3 * dp) * b2f_hi(zsu.y);
    uint2 pk;
    pk.x = (unsigned)f2b(o0) | ((unsigned)f2b(o1) << 16);
    pk.y = (unsigned)f2b(o2) | ((unsigned)f2b(o3) << 16);
    *(uint2*)(yft16 + tb + t4) = pk;
}

// ---------------- the mega kernel: 9 phases, 8 grid syncs ----------------
__global__ __launch_bounds__(256, 4) void mega_k(MegaArgs a) {
    __shared__ __align__(16) char smem[SMEM_BYTES];
    u16* gAs = (u16*)smem;
    u16* gBs = gAs + 64 * 40;
    cg::grid_group grid = cg::this_grid();
    const int gsz = gridDim.x;

    // P0: weight prep + input convert (2048 vblocks: 8 jobs x 256)
    for (int vb = blockIdx.x; vb < 2048; vb += gsz)
        prep_job(a, vb >> 8, (vb & 255) * 256 + threadIdx.x, 65536);
    grid.sync();

    // P1: conv3x3 96->96 + BN + GELU -> t1 bf16 NHWC (384 vblocks)
    for (int vb = blockIdx.x; vb < 384; vb += gsz)
        conv_body<96, 96, 32, 2>(a.Xb1, a.wt1, a.g1, a.b1, a.m1, a.v1, a.t1b,
                                 vb & 127, vb >> 7, smem);
    grid.sync();

    // P2: 1x1 conv 96->192 + BN + SiLU -> t2 bf16 (384 vblocks)
    for (int vb = blockIdx.x; vb < 384; vb += gsz)
        gemm_body<64, 1, 2>(8192, 192, 96, a.t1b, a.w2b, a.t2b,
                            a.g2, a.b2, a.m2, a.v2,
                            (vb & 127) * 64, (vb >> 7) * 64, gAs, gBs);
    grid.sync();

    // P3: in-proj: x-half -> xz bf16 row-major; z-half+SiLU -> zst bf16 transposed (1536)
    for (int vb = blockIdx.x; vb < 1536; vb += gsz) {
        int vbx = vb & 127, vby = vb >> 7;
        if (vby < 6)
            gemm_body<64, 0, 2>(8192, 384, 192, a.t2b, a.inwb, a.xzb16,
                                nullptr, nullptr, nullptr, nullptr,
                                vbx * 64, vby * 64, gAs, gBs);
        else
            gemm_body<64, 3, 4>(8192, 384, 192, a.t2b, a.inwb + (size_t)384*192, a.zst16,
                                nullptr, nullptr, nullptr, nullptr,
                                vbx * 64, (vby - 6) * 64, gAs, gBs);
    }
    grid.sync();

    // P4: depthwise causal conv + SiLU -> xcb bf16 + xct bf16 transposed (768)
    for (int vb = blockIdx.x; vb < 768; vb += gsz)
        dwconv_body(a.xzb16, a.cw, a.cb, a.xcb, a.xct16, vb & 127, vb >> 7, smem);
    grid.sync();

    // P5: dt (y<6) + x-proj Bs/Cs (y==6) -> dtt f32, dblt f32 transposed (896)
    for (int vb = blockIdx.x; vb < 896; vb += gsz) {
        int vbx = vb & 127, vby = vb >> 7;
        if (vby < 6)
            gemm_body<64, 2, 3>(8192, 384, 384, a.xcb, a.Wdt, a.dtt,
                                a.dt_b, nullptr, nullptr, nullptr,
                                vbx * 64, vby * 64, gAs, gBs);
        else
            gemm_body<32, 0, 3>(8192, 32, 384, a.xcb, a.xpb, a.dblt,
                                nullptr, nullptr, nullptr, nullptr,
                                vbx * 64, 0, gAs, gBs);
    }
    grid.sync();

    // P6: selective scan + gate -> yf bf16 [384][8192] (3072)
    for (int vb = blockIdx.x; vb < 3072; vb += gsz)
        scan_body(a.dtt, a.dblt, a.xct16, a.zst16, a.A_log, a.Dp, a.yft16, vb, smem);
    grid.sync();

    // P7: fused out-proj + 1x1 conv3 + BN + SiLU -> Xb4 bf16 (384)
    for (int vb = blockIdx.x; vb < 384; vb += gsz)
        gemm_at_body(a.yft16, a.Wow, a.Xb4, a.g3, a.b3, a.m3, a.v3,
                     vb & 127, vb >> 7, smem);
    grid.sync();

    // P8: conv3x3 192->192 + BN + GELU -> out f32 NCHW (768)
    for (int vb = blockIdx.x; vb < 768; vb += gsz)
        conv_body<192, 192, 32, 1>(a.Xb4, a.wt4, a.g4, a.b4, a.m4, a.v4, a.outp,
                                   vb & 127, vb >> 7, smem);
}

extern "C" void kernel_launch(void* const* d_in, const int* in_sizes, int n_in,
                              void* d_out, int out_size, void* d_ws, size_t ws_size,
                              hipStream_t stream) {
    float* ws = (float*)d_ws;
    u16* b16 = (u16*)(ws + O_B16);

    MegaArgs a;
    a.x     = (const float*)d_in[0];
    a.w1    = (const float*)d_in[1];
    a.g1    = (const float*)d_in[2];
    a.b1    = (const float*)d_in[3];
    a.m1    = (const float*)d_in[4];
    a.v1    = (const float*)d_in[5];
    a.w2    = (const float*)d_in[6];
    a.g2    = (const float*)d_in[7];
    a.b2    = (const float*)d_in[8];
    a.m2    = (const float*)d_in[9];
    a.v2    = (const float*)d_in[10];
    a.in_w  = (const float*)d_in[11];
    a.cw    = (const float*)d_in[12];
    a.cb    = (const float*)d_in[13];
    a.xp_w  = (const float*)d_in[14];
    a.dt_w  = (const float*)d_in[15];
    a.dt_b  = (const float*)d_in[16];
    a.A_log = (const float*)d_in[17];
    a.Dp    = (const float*)d_in[18];
    a.out_w = (const float*)d_in[19];
    a.w3    = (const float*)d_in[20];
    a.g3    = (const float*)d_in[21];
    a.b3    = (const float*)d_in[22];
    a.m3    = (const float*)d_in[23];
    a.v3    = (const float*)d_in[24];
    a.w4    = (const float*)d_in[25];
    a.g4    = (const float*)d_in[26];
    a.b4    = (const float*)d_in[27];
    a.m4    = (const float*)d_in[28];
    a.v4    = (const float*)d_in[29];

    a.xzb16 = (u16*)(ws + O_XZ);
    a.xct16 = (u16*)(ws + O_XCT);
    a.zst16 = (u16*)(ws + O_ZST);
    a.dblt  = ws + O_DBLT;
    a.yft16 = (u16*)(ws + O_YFT);
    a.dtt   = ws + O_DTT;
    a.t1b = b16 + B_T1;
    a.t2b = b16 + B_T2;
    a.xcb = b16 + B_XC;
    a.Xb1 = b16 + B_XB1;
    a.Xb4 = b16 + B_XB4;
    a.wt1 = b16 + B_WT1;
    a.wt4 = b16 + B_WT4;
    a.inwb= b16 + B_INW;
    a.w2b = b16 + B_W2;
    a.xpb = b16 + B_XP;
    a.Wdt = b16 + B_WDT;
    a.Wow = b16 + B_WOW;
    a.outp = (float*)d_out;

    int nb = 0;
    hipOccupancyMaxActiveBlocksPerMultiprocessor(&nb, mega_k, 256, 0);
    if (nb < 1) nb = 1;
    int grid = nb * 256;          // 256 CUs on MI355X
    if (grid > 3072) grid = 3072; // scan needs at most 3072

    void* args[] = { (void*)&a };
    hipLaunchCooperativeKernel((const void*)mega_k, dim3(grid), dim3(256),
                               args, 0, stream);
}

// Round 13
// 250.490 us; speedup vs baseline: 3.3514x; 3.3514x over previous
//
#include <hip/hip_runtime.h>
#include <hip/hip_bf16.h>

using u16 = unsigned short;
using short8 = __attribute__((ext_vector_type(8))) short;
using f32x4  = __attribute__((ext_vector_type(4))) float;

constexpr int DI_ = 384;

// ---- workspace layout ----
constexpr size_t O_XZ   = 0;                         // xz bf16 (8192*384 u16); later dtt f32
constexpr size_t O_XCT  = O_XZ  + (size_t)8192*384;  // xct bf16 [384][8192] u16
constexpr size_t O_ZST  = O_XCT + (size_t)384*8192;  // zst bf16 [384][8192] u16
constexpr size_t O_DBLT = O_ZST + (size_t)384*8192;  // 32*8192  Bs/Cs transposed f32
constexpr size_t O_YFT  = O_DBLT+ (size_t)32*8192;   // yf bf16 [384][8192] u16
constexpr size_t O_B16  = O_YFT + (size_t)384*8192;  // bf16 arena start
constexpr size_t O_DTT  = O_XZ;                      // overlays dead xz (f32)
// bf16 arena offsets (u16)
constexpr size_t B_T1  = 0;
constexpr size_t B_T2  = B_T1  + (size_t)8192*96;
constexpr size_t B_XC  = B_T2  + (size_t)8192*192;
constexpr size_t B_XB1 = B_XC  + (size_t)8192*384;
constexpr size_t B_XB4 = B_XB1 + (size_t)8192*96;
constexpr size_t B_WT1 = B_XB4 + (size_t)8192*192;
constexpr size_t B_WT4 = B_WT1 + (size_t)9*96*96;
constexpr size_t B_INW = B_WT4 + (size_t)9*192*192;
constexpr size_t B_W2  = B_INW + (size_t)768*192;
constexpr size_t B_XP  = B_W2  + (size_t)192*96;
constexpr size_t B_WDT = B_XP  + (size_t)32*384;
constexpr size_t B_WOW = B_WDT + (size_t)384*384;

__device__ __forceinline__ u16 f2b(float f) {
    __hip_bfloat16 h = __float2bfloat16(f);
    return *reinterpret_cast<u16*>(&h);
}
__device__ __forceinline__ float b2f(u16 u) {
    return __uint_as_float(((unsigned)u) << 16);
}
__device__ __forceinline__ float b2f_lo(unsigned u) { return __uint_as_float(u << 16); }
__device__ __forceinline__ float b2f_hi(unsigned u) { return __uint_as_float(u & 0xffff0000u); }

// ---------------- fused weight prep + input convert: 8 jobs ----------------
struct PrepArgs {
    const float *w1, *w4, *in_w, *w2, *xp_w, *dt_w, *w3, *out_w, *x;
    u16 *wt1, *wt4, *inwb, *w2b, *xpb, *Wdt, *Wow, *Xb1;
};

__global__ __launch_bounds__(256) void prep_k(PrepArgs a) {
    const int job = blockIdx.y;
    const int stride = gridDim.x * 256;
    const int i0 = blockIdx.x * 256 + threadIdx.x;
    switch (job) {
    case 0:
        for (int i = i0; i < 9*96*96; i += stride) {
            int ci = i % 96, co = (i / 96) % 96, t = i / (96*96);
            a.wt1[i] = f2b(a.w1[((size_t)co*96 + ci)*9 + t]);
        } break;
    case 1:
        for (int i = i0; i < 9*192*192; i += stride) {
            int ci = i % 192, co = (i / 192) % 192, t = i / (192*192);
            a.wt4[i] = f2b(a.w4[((size_t)co*192 + ci)*9 + t]);
        } break;
    case 2:
        for (int i = i0; i < 768*192; i += stride) a.inwb[i] = f2b(a.in_w[i]);
        break;
    case 3:
        for (int i = i0; i < 192*96; i += stride) a.w2b[i] = f2b(a.w2[i]);
        break;
    case 4: // xp_w rows 12..43 -> [32][384]
        for (int i = i0; i < 32*384; i += stride) {
            int r = i / 384, c = i % 384;
            a.xpb[i] = f2b(a.xp_w[(size_t)(12 + r)*384 + c]);
        } break;
    case 5: // Wdt = dt_w @ xp_w[:12]
        for (int i = i0; i < 384*384; i += stride) {
            int r = i / 384, c = i % 384;
            float s = 0.f;
            #pragma unroll
            for (int k = 0; k < 12; ++k) s += a.dt_w[r*12 + k] * a.xp_w[(size_t)k*384 + c];
            a.Wdt[i] = f2b(s);
        } break;
    case 6: // Wow = w3 @ out_w
        for (int i = i0; i < 192*384; i += stride) {
            int o = i / 384, d = i % 384;
            float s = 0.f;
            for (int j = 0; j < 192; ++j) s += a.w3[(size_t)o*192 + j] * a.out_w[(size_t)j*384 + d];
            a.Wow[i] = f2b(s);
        } break;
    case 7: // x NCHW f32 -> NHWC bf16
        for (int i = i0; i < 8192*96; i += stride) {
            int ci = i % 96, px = i / 96;
            a.Xb1[i] = f2b(a.x[(((size_t)(px >> 10) * 96 + ci) << 10) | (size_t)(px & 1023)]);
        } break;
    }
}

// ---------------- 3x3 conv: halo-staged bf16-MFMA + BN + exact GELU ----------------
// OUTM 1: f32 NCHW out (LDS-transposed, coalesced); 2: bf16 NHWC out.
template<int CIN, int COUT, int NTILE, int OUTM>
__global__ __launch_bounds__(256) void conv3x3_mfma_k(
    const u16* __restrict__ Xb, const u16* __restrict__ Wt,
    const float* __restrict__ g, const float* __restrict__ b,
    const float* __restrict__ m, const float* __restrict__ v,
    void* __restrict__ out)
{
    constexpr int LD = 40;
    constexpr int NT = NTILE / 16;
    __shared__ u16 As[4 * 36 * LD];
    __shared__ u16 Bs[9 * NTILE * LD];
    const int tid = threadIdx.x;
    const int wave = tid >> 6, lane = tid & 63;
    const int quad = lane >> 4, l16 = lane & 15;
    const int rowBase = blockIdx.x * 64;
    const int colBase = blockIdx.y * NTILE;
    const int img = rowBase >> 10;
    const int imgRow0 = (rowBase & 1023) >> 5;

    if (tid < 160) {
        int slot8 = tid / 20;
        int off = tid % 20;
        int hrow = slot8 >> 1;
        int hcol = (slot8 & 1) ? 33 : 0;
        ((unsigned*)As)[((hrow * 36 + hcol) * LD) / 2 + off] = 0u;
    }

    f32x4 acc[NT];
    #pragma unroll
    for (int nt = 0; nt < NT; ++nt)
        #pragma unroll
        for (int i = 0; i < 4; ++i) acc[nt][i] = 0.f;

    const int pxl = wave * 16 + l16;
    const int prow = pxl >> 5, pcol = pxl & 31;

    for (int ci0 = 0; ci0 < CIN; ci0 += 32) {
        __syncthreads();
        #pragma unroll
        for (int it = 0; it < 2; ++it) {
            int id = tid + it * 256;
            int pix = id >> 2, seg = id & 3;
            int hrow = pix >> 5, hcol = pix & 31;
            int grow = imgRow0 - 1 + hrow;
            uint4 va = make_uint4(0u, 0u, 0u, 0u);
            if ((unsigned)grow < 32u)
                va = *(const uint4*)(Xb +
                    (size_t)((img << 10) + (grow << 5) + hcol) * CIN + ci0 + seg * 8);
            *(uint4*)(As + (hrow * 36 + hcol + 1) * LD + seg * 8) = va;
        }
        constexpr int BT = 9 * NTILE * 4;
        for (int id = tid; id < BT; id += 256) {
            int t = id / (NTILE * 4);
            int r = (id >> 2) & (NTILE - 1);
            int seg = id & 3;
            uint4 vb = *(const uint4*)(Wt +
                ((size_t)t * COUT + colBase + r) * CIN + ci0 + seg * 8);
            *(uint4*)(Bs + (t * NTILE + r) * LD + seg * 8) = vb;
        }
        __syncthreads();
        #pragma unroll
        for (int t = 0; t < 9; ++t) {
            const int dr = t / 3 - 1, dc = t % 3 - 1;
            short8 a = *(const short8*)(As +
                ((prow + 1 + dr) * 36 + (pcol + 1 + dc)) * LD + quad * 8);
            #pragma unroll
            for (int nt = 0; nt < NT; ++nt) {
                short8 bf = *(const short8*)(Bs + (t * NTILE + nt * 16 + l16) * LD + quad * 8);
                acc[nt] = __builtin_amdgcn_mfma_f32_16x16x32_bf16(a, bf, acc[nt], 0, 0, 0);
            }
        }
    }

    const int px0 = rowBase + wave * 16 + quad * 4;
    if (OUTM == 2) {
        #pragma unroll
        for (int nt = 0; nt < NT; ++nt) {
            const int co = colBase + nt * 16 + l16;
            const float sc = g[co] * rsqrtf(v[co] + 1e-5f);
            const float bb = b[co] - m[co] * sc;
            #pragma unroll
            for (int r = 0; r < 4; ++r) {
                float xv = acc[nt][r] * sc + bb;
                float gel = 0.5f * xv * (1.f + erff(xv * 0.70710678f));
                ((u16*)out)[(size_t)(px0 + r) * COUT + co] = f2b(gel);
            }
        }
    } else {
        float* Tout = (float*)As;   // NTILE*68*4 <= 11520 B for NTILE=32
        const int pxl0 = wave * 16 + quad * 4;
        __syncthreads();
        #pragma unroll
        for (int nt = 0; nt < NT; ++nt) {
            const int co = colBase + nt * 16 + l16;
            const float sc = g[co] * rsqrtf(v[co] + 1e-5f);
            const float bb = b[co] - m[co] * sc;
            #pragma unroll
            for (int r = 0; r < 4; ++r) {
                float xv = acc[nt][r] * sc + bb;
                Tout[(nt * 16 + l16) * 68 + pxl0 + r] =
                    0.5f * xv * (1.f + erff(xv * 0.70710678f));
            }
        }
        __syncthreads();
        const int off0 = rowBase & 1023;
        for (int s = tid; s < NTILE * 16; s += 256) {
            int co = s >> 4, p4 = s & 15;
            float4 vv = *(const float4*)(Tout + co * 68 + p4 * 4);
            *(float4*)((float*)out + (((size_t)img * COUT + colBase + co) << 10)
                       + off0 + p4 * 4) = vv;
        }
    }
}

// ---------------- shared MFMA GEMM body ----------------
// EPI: 0 none, 1 BN+SiLU, 2 softplus+bias, 3 SiLU.
// OUTM: 0 f32 row-major, 2 bf16 row-major, 3 f32 transposed, 4 bf16 transposed.
template<int NTILE, int EPI, int OUTM>
__device__ __forceinline__ void gemm_body(
    int M, int N, int K,
    const u16* __restrict__ Ab, const u16* __restrict__ Bb, void* __restrict__ C,
    const float* __restrict__ p0, const float* __restrict__ p1,
    const float* __restrict__ p2, const float* __restrict__ p3,
    int rowBase, int colBase, u16* As, u16* Bs)
{
    constexpr int LDA = 40;
    constexpr int NT = NTILE / 16;
    const int tid = threadIdx.x;
    const int wave = tid >> 6, lane = tid & 63;
    const int quad = lane >> 4, l16 = lane & 15;

    f32x4 acc[NT];
    #pragma unroll
    for (int nt = 0; nt < NT; ++nt)
        #pragma unroll
        for (int i = 0; i < 4; ++i) acc[nt][i] = 0.f;

    const int ar = tid >> 2, aseg = tid & 3;

    for (int k0 = 0; k0 < K; k0 += 32) {
        __syncthreads();
        uint4 va = *(const uint4*)(Ab + (size_t)(rowBase + ar) * K + k0 + aseg * 8);
        *(uint4*)(As + ar * LDA + aseg * 8) = va;
        if (tid < NTILE * 4) {
            int r = tid >> 2, seg = tid & 3;
            uint4 vb = *(const uint4*)(Bb + (size_t)(colBase + r) * K + k0 + seg * 8);
            *(uint4*)(Bs + r * LDA + seg * 8) = vb;
        }
        __syncthreads();
        short8 a = *(const short8*)(As + (wave * 16 + l16) * LDA + quad * 8);
        #pragma unroll
        for (int nt = 0; nt < NT; ++nt) {
            short8 bf = *(const short8*)(Bs + (nt * 16 + l16) * LDA + quad * 8);
            acc[nt] = __builtin_amdgcn_mfma_f32_16x16x32_bf16(a, bf, acc[nt], 0, 0, 0);
        }
    }

    const int px0 = rowBase + wave * 16 + quad * 4;
    #pragma unroll
    for (int nt = 0; nt < NT; ++nt) {
        const int co = colBase + nt * 16 + l16;
        float sc = 0.f, bb = 0.f;
        if (EPI == 1) {
            sc = p0[co] * rsqrtf(p3[co] + 1e-5f);
            bb = p1[co] - p2[co] * sc;
        } else if (EPI == 2) {
            bb = p0[co];
        }
        float o[4];
        #pragma unroll
        for (int r = 0; r < 4; ++r) {
            float xv = acc[nt][r];
            if (EPI == 1) {
                xv = xv * sc + bb;
                xv = xv / (1.f + __expf(-xv));
            } else if (EPI == 2) {
                xv += bb;
                xv = (xv > 20.f) ? xv : log1pf(__expf(xv));
            } else if (EPI == 3) {
                xv = xv / (1.f + __expf(-xv));
            }
            o[r] = xv;
        }
        if (OUTM == 3) {
            *(float4*)((float*)C + (size_t)co * M + px0) =
                make_float4(o[0], o[1], o[2], o[3]);
        } else if (OUTM == 4) {
            uint2 pk;
            pk.x = (unsigned)f2b(o[0]) | ((unsigned)f2b(o[1]) << 16);
            pk.y = (unsigned)f2b(o[2]) | ((unsigned)f2b(o[3]) << 16);
            *(uint2*)((u16*)C + (size_t)co * M + px0) = pk;
        } else if (OUTM == 2) {
            #pragma unroll
            for (int r = 0; r < 4; ++r)
                ((u16*)C)[(size_t)(px0 + r) * N + co] = f2b(o[r]);
        } else {
            #pragma unroll
            for (int r = 0; r < 4; ++r)
                ((float*)C)[(size_t)(px0 + r) * N + co] = o[r];
        }
    }
}

template<int NTILE, int EPI, int OUTM>
__global__ __launch_bounds__(256) void gemm_mfma_k(
    int M, int N, int K,
    const u16* __restrict__ Ab, const u16* __restrict__ Bb, void* __restrict__ C,
    const float* __restrict__ p0, const float* __restrict__ p1,
    const float* __restrict__ p2, const float* __restrict__ p3)
{
    __shared__ u16 As[64 * 40];
    __shared__ u16 Bs[NTILE * 40];
    gemm_body<NTILE, EPI, OUTM>(M, N, K, Ab, Bb, C, p0, p1, p2, p3,
                                blockIdx.x * 64, blockIdx.y * NTILE, As, Bs);
}

// ---------------- combined in-proj: x-half -> bf16 rowmajor; z-half -> bf16 transposed+SiLU ----------------
__global__ __launch_bounds__(256) void ip_k(
    const u16* __restrict__ t2b, const u16* __restrict__ inwb,
    u16* __restrict__ xzb16, u16* __restrict__ zst16)
{
    __shared__ u16 As[64 * 40];
    __shared__ u16 Bs[64 * 40];
    if (blockIdx.y < 6) {
        gemm_body<64, 0, 2>(8192, 384, 192, t2b, inwb, xzb16,
                            nullptr, nullptr, nullptr, nullptr,
                            blockIdx.x * 64, blockIdx.y * 64, As, Bs);
    } else {
        gemm_body<64, 3, 4>(8192, 384, 192, t2b, inwb + (size_t)384*192, zst16,
                            nullptr, nullptr, nullptr, nullptr,
                            blockIdx.x * 64, (blockIdx.y - 6) * 64, As, Bs);
    }
}

// ---------------- combined x-proj + dt dispatch ----------------
__global__ __launch_bounds__(256) void pd_k(
    const u16* __restrict__ xcb, const u16* __restrict__ Wdt,
    const u16* __restrict__ xpb, const float* __restrict__ dt_b,
    float* __restrict__ dtt, float* __restrict__ dblt)
{
    __shared__ u16 As[64 * 40];
    __shared__ u16 Bs[64 * 40];
    if (blockIdx.y < 6) {
        gemm_body<64, 2, 3>(8192, 384, 384, xcb, Wdt, dtt, dt_b, nullptr, nullptr, nullptr,
                            blockIdx.x * 64, blockIdx.y * 64, As, Bs);
    } else {
        gemm_body<32, 0, 3>(8192, 32, 384, xcb, xpb, dblt, nullptr, nullptr, nullptr, nullptr,
                            blockIdx.x * 64, 0, As, Bs);
    }
}

// ---------------- out-proj GEMM with bf16 transposed-A staging ----------------
__global__ __launch_bounds__(256) void gemm_at_k(
    const u16* __restrict__ At, const u16* __restrict__ Bb, u16* __restrict__ C,
    const float* __restrict__ p0, const float* __restrict__ p1,
    const float* __restrict__ p2, const float* __restrict__ p3)
{
    constexpr int LDA = 40;
    constexpr int NTILE = 64, NT = 4;
    constexpr int M = 8192, N = 192, K = 384;
    __shared__ u16 As[64 * LDA];
    __shared__ u16 Bs[NTILE * LDA];
    const int tid = threadIdx.x;
    const int wave = tid >> 6, lane = tid & 63;
    const int quad = lane >> 4, l16 = lane & 15;
    const int rowBase = blockIdx.x * 64;
    const int colBase = blockIdx.y * NTILE;

    f32x4 acc[NT];
    #pragma unroll
    for (int nt = 0; nt < NT; ++nt)
        #pragma unroll
        for (int i = 0; i < 4; ++i) acc[nt][i] = 0.f;

    const int krow = tid >> 3, mseg = tid & 7;

    for (int k0 = 0; k0 < K; k0 += 32) {
        __syncthreads();
        uint4 va = *(const uint4*)(At + (size_t)(k0 + krow) * M + rowBase + mseg * 8);
        const u16* pv = (const u16*)&va;
        #pragma unroll
        for (int j = 0; j < 8; ++j)
            As[(mseg * 8 + j) * LDA + krow] = pv[j];
        if (tid < NTILE * 4) {
            int r = tid >> 2, seg = tid & 3;
            uint4 vb = *(const uint4*)(Bb + (size_t)(colBase + r) * K + k0 + seg * 8);
            *(uint4*)(Bs + r * LDA + seg * 8) = vb;
        }
        __syncthreads();
        short8 a = *(const short8*)(As + (wave * 16 + l16) * LDA + quad * 8);
        #pragma unroll
        for (int nt = 0; nt < NT; ++nt) {
            short8 bf = *(const short8*)(Bs + (nt * 16 + l16) * LDA + quad * 8);
            acc[nt] = __builtin_amdgcn_mfma_f32_16x16x32_bf16(a, bf, acc[nt], 0, 0, 0);
        }
    }

    const int px0 = rowBase + wave * 16 + quad * 4;
    #pragma unroll
    for (int nt = 0; nt < NT; ++nt) {
        const int co = colBase + nt * 16 + l16;
        const float sc = p0[co] * rsqrtf(p3[co] + 1e-5f);
        const float bb = p1[co] - p2[co] * sc;
        #pragma unroll
        for (int r = 0; r < 4; ++r) {
            float xv = acc[nt][r] * sc + bb;
            xv = xv / (1.f + __expf(-xv));
            C[(size_t)(px0 + r) * N + co] = f2b(xv);
        }
    }
}

// ---------------- depthwise causal conv (K=4) + SiLU, bf16 in/out ----------------
__global__ __launch_bounds__(256) void dwconv_k(
    const u16* __restrict__ xz16, const float* __restrict__ cw, const float* __restrict__ cb,
    u16* __restrict__ xcb, u16* __restrict__ xct16)
{
    __shared__ float T[64][65];
    const int tid = threadIdx.x;
    const int cl = tid & 63, rq = tid >> 6;
    const int mBase = blockIdx.x * 64, cBase = blockIdx.y * 64;
    const int c = cBase + cl;
    const float w0 = cw[c*4+0], w1 = cw[c*4+1], w2 = cw[c*4+2], w3 = cw[c*4+3];
    const float bias = cb[c];
    #pragma unroll
    for (int rr = 0; rr < 16; ++rr) {
        int ml = rr * 4 + rq;
        int bl = mBase + ml;
        int l = bl & 1023;
        float acc = bias + b2f(xz16[(size_t)bl * 384 + c]) * w3;
        if (l >= 1) acc += b2f(xz16[(size_t)(bl-1) * 384 + c]) * w2;
        if (l >= 2) acc += b2f(xz16[(size_t)(bl-2) * 384 + c]) * w1;
        if (l >= 3) acc += b2f(xz16[(size_t)(bl-3) * 384 + c]) * w0;
        float s = acc / (1.f + __expf(-acc));
        xcb[(size_t)bl * DI_ + c] = f2b(s);
        T[ml][cl] = s;
    }
    __syncthreads();
    #pragma unroll
    for (int rr = 0; rr < 16; ++rr) {
        int dl = rr * 4 + rq;
        xct16[(size_t)(cBase + dl) * 8192 + mBase + cl] = f2b(T[cl][dl]);
    }
}

// ---------------- selective scan: LDS-combine, exp-of-sum; bf16 xc/z, bf16 yf out ----------------
__global__ __launch_bounds__(256) void scan_k(
    const float* __restrict__ dtt, const float* __restrict__ dblt,
    const u16* __restrict__ xct16, const u16* __restrict__ zst16,
    const float* __restrict__ A_log, const float* __restrict__ Dp,
    u16* __restrict__ yft16)
{
    const int bd = blockIdx.x;
    const int b = bd / DI_, d = bd % DI_;
    const int tid = threadIdx.x;
    const size_t tb = (size_t)d * 8192 + (size_t)b * 1024;
    const size_t nb = (size_t)b * 1024;
    const int t4 = tid * 4;

    __shared__ float LH[16][257];
    __shared__ float SD[257];
    __shared__ float SH[16][17];
    __shared__ float SP[16][17];
    __shared__ float SSD[17];
    __shared__ float AndS[16];

    const float4 dt4 = *(const float4*)(dtt + tb + t4);
    const uint2 xcu = *(const uint2*)(xct16 + tb + t4);
    const float xc0 = b2f_lo(xcu.x), xc1 = b2f_hi(xcu.x);
    const float xc2 = b2f_lo(xcu.y), xc3 = b2f_hi(xcu.y);
    const float dtxc[4] = {dt4.x*xc0, dt4.y*xc1, dt4.z*xc2, dt4.w*xc3};

    float And[16];
    #pragma unroll
    for (int n = 0; n < 16; ++n) And[n] = -__expf(A_log[d*16 + n]);
    if (tid < 16) AndS[tid] = -__expf(A_log[d*16 + tid]);
    SD[tid] = dt4.x + dt4.y + dt4.z + dt4.w;

    #pragma unroll
    for (int n = 0; n < 16; ++n) {
        const float4 bs4 = *(const float4*)(dblt + (size_t)n * 8192 + nb + t4);
        float h = dtxc[0] * bs4.x;
        h = __expf(dt4.y * And[n]) * h + dtxc[1] * bs4.y;
        h = __expf(dt4.z * And[n]) * h + dtxc[2] * bs4.z;
        h = __expf(dt4.w * And[n]) * h + dtxc[3] * bs4.w;
        LH[n][tid] = h;
    }
    __syncthreads();

    {
        const int n = tid & 15, s = tid >> 4;
        const float An = AndS[n];
        float H = 0.f, ssd = 0.f;
        #pragma unroll
        for (int k = 0; k < 16; ++k) {
            const int c = s * 16 + k;
            float sd = SD[c];
            H = __expf(An * sd) * H + LH[n][c];
            ssd += sd;
        }
        SH[n][s] = H;
        if (n == 0) SSD[s] = ssd;
    }
    __syncthreads();

    if (tid < 16) {
        const float An = AndS[tid];
        float Hp = 0.f;
        #pragma unroll
        for (int s = 0; s < 16; ++s) {
            SP[tid][s] = Hp;
            Hp = __expf(An * SSD[s]) * Hp + SH[tid][s];
        }
    }
    __syncthreads();

    {
        const int n = tid & 15, s = tid >> 4;
        const float An = AndS[n];
        float st = SP[n][s];
        #pragma unroll
        for (int k = 0; k < 16; ++k) {
            const int c = s * 16 + k;
            float a = __expf(An * SD[c]);
            float h = LH[n][c];
            LH[n][c] = st;
            st = a * st + h;
        }
    }
    __syncthreads();

    float y0 = 0.f, y1 = 0.f, y2 = 0.f, y3 = 0.f;
    #pragma unroll
    for (int n = 0; n < 16; ++n) {
        float h = LH[n][tid];
        const float4 bs4 = *(const float4*)(dblt + (size_t)n * 8192 + nb + t4);
        const float4 cs4 = *(const float4*)(dblt + (size_t)(16 + n) * 8192 + nb + t4);
        h = __expf(dt4.x * And[n]) * h + dtxc[0]*bs4.x; y0 += h * cs4.x;
        h = __expf(dt4.y * And[n]) * h + dtxc[1]*bs4.y; y1 += h * cs4.y;
        h = __expf(dt4.z * And[n]) * h + dtxc[2]*bs4.z; y2 += h * cs4.z;
        h = __expf(dt4.w * And[n]) * h + dtxc[3]*bs4.w; y3 += h * cs4.w;
    }
    const float dp = Dp[d];
    const uint2 zsu = *(const uint2*)(zst16 + tb + t4);
    float o0 = (y0 + xc0 * dp) * b2f_lo(zsu.x);
    float o1 = (y1 + xc1 * dp) * b2f_hi(zsu.x);
    float o2 = (y2 + xc2 * dp) * b2f_lo(zsu.y);
    float o3 = (y3 + xc3 * dp) * b2f_hi(zsu.y);
    uint2 pk;
    pk.x = (unsigned)f2b(o0) | ((unsigned)f2b(o1) << 16);
    pk.y = (unsigned)f2b(o2) | ((unsigned)f2b(o3) << 16);
    *(uint2*)(yft16 + tb + t4) = pk;
}

extern "C" void kernel_launch(void* const* d_in, const int* in_sizes, int n_in,
                              void* d_out, int out_size, void* d_ws, size_t ws_size,
                              hipStream_t stream) {
    const float* x     = (const float*)d_in[0];
    const float* w1    = (const float*)d_in[1];
    const float* g1    = (const float*)d_in[2];
    const float* b1    = (const float*)d_in[3];
    const float* m1    = (const float*)d_in[4];
    const float* v1    = (const float*)d_in[5];
    const float* w2    = (const float*)d_in[6];
    const float* g2    = (const float*)d_in[7];
    const float* b2    = (const float*)d_in[8];
    const float* m2    = (const float*)d_in[9];
    const float* v2    = (const float*)d_in[10];
    const float* in_w  = (const float*)d_in[11];
    const float* cw    = (const float*)d_in[12];
    const float* cb    = (const float*)d_in[13];
    const float* xp_w  = (const float*)d_in[14];
    const float* dt_w  = (const float*)d_in[15];
    const float* dt_b  = (const float*)d_in[16];
    const float* A_log = (const float*)d_in[17];
    const float* Dp    = (const float*)d_in[18];
    const float* out_w = (const float*)d_in[19];
    const float* w3    = (const float*)d_in[20];
    const float* g3    = (const float*)d_in[21];
    const float* b3    = (const float*)d_in[22];
    const float* m3    = (const float*)d_in[23];
    const float* v3    = (const float*)d_in[24];
    const float* w4    = (const float*)d_in[25];
    const float* g4    = (const float*)d_in[26];
    const float* b4    = (const float*)d_in[27];
    const float* m4    = (const float*)d_in[28];
    const float* v4    = (const float*)d_in[29];

    float* ws   = (float*)d_ws;
    u16*   xzb16 = (u16*)(ws + O_XZ);
    u16*   xct16 = (u16*)(ws + O_XCT);
    u16*   zst16 = (u16*)(ws + O_ZST);
    float* dblt = ws + O_DBLT;
    u16*   yft16 = (u16*)(ws + O_YFT);
    float* dtt  = ws + O_DTT;
    u16* b16  = (u16*)(ws + O_B16);
    u16* t1b  = b16 + B_T1;
    u16* t2b  = b16 + B_T2;
    u16* xcb  = b16 + B_XC;
    u16* Xb1  = b16 + B_XB1;
    u16* Xb4  = b16 + B_XB4;
    u16* wt1  = b16 + B_WT1;
    u16* wt4  = b16 + B_WT4;
    u16* inwb = b16 + B_INW;
    u16* w2b  = b16 + B_W2;
    u16* xpb  = b16 + B_XP;
    u16* Wdt  = b16 + B_WDT;
    u16* Wow  = b16 + B_WOW;

    // 0) weight prep + input convert (8 jobs)
    PrepArgs pa;
    pa.w1 = w1; pa.w4 = w4; pa.in_w = in_w; pa.w2 = w2; pa.xp_w = xp_w;
    pa.dt_w = dt_w; pa.w3 = w3; pa.out_w = out_w; pa.x = x;
    pa.wt1 = wt1; pa.wt4 = wt4; pa.inwb = inwb; pa.w2b = w2b; pa.xpb = xpb;
    pa.Wdt = Wdt; pa.Wow = Wow; pa.Xb1 = Xb1;
    prep_k<<<dim3(256, 8), 256, 0, stream>>>(pa);

    // 1) conv3x3 96->96 + BN + GELU (halo MFMA) -> t1 bf16 NHWC
    conv3x3_mfma_k<96, 96, 32, 2><<<dim3(128, 3), 256, 0, stream>>>(
        Xb1, wt1, g1, b1, m1, v1, t1b);

    // 2) 1x1 conv 96->192 + BN + SiLU -> t2 bf16
    gemm_mfma_k<64, 1, 2><<<dim3(128, 3), 256, 0, stream>>>(
        8192, 192, 96, t1b, w2b, t2b, g2, b2, m2, v2);

    // 3) in-proj: x-half -> xzb16 bf16 row-major; z-half + SiLU -> zst16 bf16 transposed
    ip_k<<<dim3(128, 12), 256, 0, stream>>>(t2b, inwb, xzb16, zst16);

    // 4) depthwise causal conv + SiLU -> xcb bf16 + xct16 bf16 transposed
    dwconv_k<<<dim3(128, 6), 256, 0, stream>>>(xzb16, cw, cb, xcb, xct16);

    // 5) combined: dt (y<6) + x-proj Bs/Cs (y==6) -> dtt f32, dblt f32 (transposed)
    pd_k<<<dim3(128, 7), 256, 0, stream>>>(xcb, Wdt, xpb, dt_b, dtt, dblt);

    // 6) selective scan + gate -> yft16 bf16 [384][8192]
    scan_k<<<8 * DI_, 256, 0, stream>>>(dtt, dblt, xct16, zst16, A_log, Dp, yft16);

    // 7) fused out-proj + 1x1 conv3 + BN + SiLU (bf16 transposed-A MFMA) -> Xb4 bf16
    gemm_at_k<<<dim3(128, 3), 256, 0, stream>>>(
        yft16, Wow, Xb4, g3, b3, m3, v3);

    // 8) conv3x3 192->192 + BN + GELU (halo MFMA) -> out f32 NCHW (coalesced)
    conv3x3_mfma_k<192, 192, 32, 1><<<dim3(128, 6), 256, 0, stream>>>(
        Xb4, wt4, g4, b4, m4, v4, (float*)d_out);
}